// Round 13
// baseline (385.757 us; speedup 1.0000x reference)
//
#include <hip/hip_runtime.h>

#define N_NODES 200000
#define N_EDGES 3200000
#define N_GRAPHS 1024
#define HD 16
#define ALPHA_ 0.2f

#define BNODES 512                 // nodes per bucket (dst >> 9)
#define NBUCK 391                  // ceil(N_NODES/512)
#define CHUNKA 8192                // edges per pass-A block
#define NBLKA 391                  // ceil(N_EDGES/8192)
#define PERA 2                     // ceil(NBLKA/256)

typedef unsigned long long u64;
#define NTL(p) __builtin_nontemporal_load(p)

// ---------- radix pass 1: bucket by dst>>9 (int LDS atomics only) ----------
__global__ __launch_bounds__(256) void hist_kernel(const int* __restrict__ dst,
                                                   int* __restrict__ blkhist) {
    __shared__ int hist[NBUCK];
    int t = threadIdx.x;
    for (int i = t; i < NBUCK; i += 256) hist[i] = 0;
    __syncthreads();
    int e0 = blockIdx.x * CHUNKA;
    int e1 = min(e0 + CHUNKA, N_EDGES);
#pragma unroll
    for (int k = 0; k < 8; ++k) {
        int e = e0 + (k << 10) + (t << 2);
        if (e < e1) {   // e, e1 multiples of 4 -> full int4 valid
            int4 d4 = *(const int4*)(dst + e);
            atomicAdd(&hist[d4.x >> 9], 1);
            atomicAdd(&hist[d4.y >> 9], 1);
            atomicAdd(&hist[d4.z >> 9], 1);
            atomicAdd(&hist[d4.w >> 9], 1);
        }
    }
    __syncthreads();
    int* out = blkhist + (size_t)blockIdx.x * NBUCK;
    for (int i = t; i < NBUCK; i += 256) out[i] = hist[i];
}

// column-wise exclusive scan across NBLKA blocks; totals -> bstart
__global__ __launch_bounds__(256) void scanA_kernel(int* __restrict__ blkhist,
                                                    int* __restrict__ bstart) {
    __shared__ int s[256];
    int u = blockIdx.x, t = threadIdx.x;
    int v[PERA];
    int sum = 0;
#pragma unroll
    for (int i = 0; i < PERA; ++i) {
        int j = t * PERA + i;
        v[i] = (j < NBLKA) ? blkhist[(size_t)j * NBUCK + u] : 0;
        sum += v[i];
    }
    s[t] = sum;
    __syncthreads();
    for (int off = 1; off < 256; off <<= 1) {
        int x = (t >= off) ? s[t - off] : 0;
        __syncthreads();
        s[t] += x;
        __syncthreads();
    }
    int run = s[t] - sum;
#pragma unroll
    for (int i = 0; i < PERA; ++i) {
        int j = t * PERA + i;
        if (j < NBLKA) blkhist[(size_t)j * NBUCK + u] = run;
        run += v[i];
    }
    if (t == 255) bstart[u] = s[255];
}

// exclusive scan over bucket totals (single block)
__global__ __launch_bounds__(256) void scanB_kernel(int* __restrict__ bstart) {
    __shared__ int s[256];
    int t = threadIdx.x;
    int v[2];
    int sum = 0;
#pragma unroll
    for (int i = 0; i < 2; ++i) {
        int j = t * 2 + i;
        v[i] = (j < NBUCK) ? bstart[j] : 0;
        sum += v[i];
    }
    s[t] = sum;
    __syncthreads();
    for (int off = 1; off < 256; off <<= 1) {
        int x = (t >= off) ? s[t - off] : 0;
        __syncthreads();
        s[t] += x;
        __syncthreads();
    }
    int run = s[t] - sum;
#pragma unroll
    for (int i = 0; i < 2; ++i) {
        int j = t * 2 + i;
        if (j < NBUCK) bstart[j] = run;
        run += v[i];
    }
    if (t == 255) bstart[NBUCK] = s[255];
}

// entry = (ea:32 | dlow:9 | src:18)
__global__ __launch_bounds__(256) void scatter_kernel(const int* __restrict__ src,
                                                      const int* __restrict__ dst,
                                                      const float* __restrict__ ea,
                                                      const int* __restrict__ blkhist,
                                                      const int* __restrict__ bstart,
                                                      u64* __restrict__ bucketed) {
    __shared__ int cursor[NBUCK];
    int t = threadIdx.x;
    const int* bo = blkhist + (size_t)blockIdx.x * NBUCK;
    for (int i = t; i < NBUCK; i += 256) cursor[i] = bstart[i] + bo[i];
    __syncthreads();
    int e0 = blockIdx.x * CHUNKA;
    int e1 = min(e0 + CHUNKA, N_EDGES);
#pragma unroll
    for (int k = 0; k < 8; ++k) {
        int e = e0 + (k << 10) + (t << 2);
        if (e < e1) {   // full int4/float4 valid (multiples of 4)
            int4   d4 = *(const int4*)(dst + e);
            int4   s4 = *(const int4*)(src + e);
            float4 a4 = *(const float4*)(ea + e);
            int p0 = atomicAdd(&cursor[d4.x >> 9], 1);
            int p1 = atomicAdd(&cursor[d4.y >> 9], 1);
            int p2 = atomicAdd(&cursor[d4.z >> 9], 1);
            int p3 = atomicAdd(&cursor[d4.w >> 9], 1);
            bucketed[p0] = ((u64)__float_as_uint(a4.x) << 32) | (unsigned)(s4.x | ((d4.x & 511) << 18));
            bucketed[p1] = ((u64)__float_as_uint(a4.y) << 32) | (unsigned)(s4.y | ((d4.y & 511) << 18));
            bucketed[p2] = ((u64)__float_as_uint(a4.z) << 32) | (unsigned)(s4.z | ((d4.z & 511) << 18));
            bucketed[p3] = ((u64)__float_as_uint(a4.w) << 32) | (unsigned)(s4.w | ((d4.w & 511) << 18));
        }
    }
}

// radix pass 2: in-bucket counting sort by dlow (9b, int LDS atomics) + fused
// per-node weighted degree -> dinv, dx = {dinv, dinv*x}. 512 nodes/bucket, 2/thread.
__global__ __launch_bounds__(256) void sortd_kernel(const u64* __restrict__ bucketed,
                                                    const int* __restrict__ bstart,
                                                    const float* __restrict__ x,
                                                    u64* __restrict__ sorted,
                                                    int* __restrict__ nodeoff,
                                                    float* __restrict__ dinv,
                                                    float2* __restrict__ dx) {
    __shared__ int hist[512];
    __shared__ int s[256];
    __shared__ int cur[512];
    int u = blockIdx.x, t = threadIdx.x;
    hist[t] = 0;
    hist[t + 256] = 0;
    __syncthreads();
    int b0 = bstart[u], b1 = bstart[u + 1];
    for (int i = b0 + t; i < b1; i += 256)
        atomicAdd(&hist[(int)((bucketed[i] >> 18) & 511u)], 1);
    __syncthreads();
    int c0 = hist[2 * t], c1 = hist[2 * t + 1];
    int pair = c0 + c1;
    s[t] = pair;
    __syncthreads();
    for (int off = 1; off < 256; off <<= 1) {
        int v = (t >= off) ? s[t - off] : 0;
        __syncthreads();
        s[t] += v;
        __syncthreads();
    }
    int run = s[t] - pair;           // exclusive prefix over pairs
    int loc0 = b0 + run, loc1 = b0 + run + c0;
    cur[2 * t] = loc0;
    cur[2 * t + 1] = loc1;
    int n0 = u * BNODES + 2 * t, n1 = n0 + 1;
    if (n0 < N_NODES) nodeoff[n0] = loc0;
    if (n1 < N_NODES) nodeoff[n1] = loc1;
    __syncthreads();
    for (int i = b0 + t; i < b1; i += 256) {
        u64 ent = bucketed[i];
        int pos = atomicAdd(&cur[(int)((ent >> 18) & 511u)], 1);
        sorted[pos] = ent;
    }
    __syncthreads();
    // per-node serial weighted degree over own contiguous range (L1/L2-hot)
    if (n0 < N_NODES) {
        float sum = 0.f;
        for (int k = 0; k < c0; ++k)
            sum += __uint_as_float((unsigned)(sorted[loc0 + k] >> 32));
        float dn = rsqrtf(sum + 1.0f);
        dinv[n0] = dn;
        dx[n0] = make_float2(dn, dn * x[n0]);
    }
    if (n1 < N_NODES) {
        float sum = 0.f;
        for (int k = 0; k < c1; ++k)
            sum += __uint_as_float((unsigned)(sorted[loc1 + k] >> 32));
        float dn = rsqrtf(sum + 1.0f);
        dinv[n1] = dn;
        dx[n1] = make_float2(dn, dn * x[n1]);
    }
}

// layer 0: 2 threads/node (stride-2 halves, shfl_xor combine) — doubles wave
// count vs thread-per-node (12 -> 24 waves/CU; latency-bound gather needs TLP)
__global__ __launch_bounds__(256) void agg0_kernel(const u64* __restrict__ sorted,
                                                   const int* __restrict__ nodeoff,
                                                   const float2* __restrict__ dx,
                                                   float2* __restrict__ db0,
                                                   float* __restrict__ s1v) {
    int t = threadIdx.x;
    int n = blockIdx.x * 128 + (t >> 1);
    int h = t & 1;
    float acc = 0.f, wsum = 0.f;
    if (n < N_NODES) {
        int e0 = nodeoff[n];
        int e1 = (n < N_NODES - 1) ? nodeoff[n + 1] : N_EDGES;
        int i = e0 + h;
        for (; i + 2 < e1; i += 4) {
            u64 en0 = sorted[i], en1 = sorted[i + 2];
            float2 g0 = dx[(int)(en0 & 0x3ffffu)];
            float2 g1 = dx[(int)(en1 & 0x3ffffu)];
            float a0 = __uint_as_float((unsigned)(en0 >> 32));
            float a1 = __uint_as_float((unsigned)(en1 >> 32));
            acc += a0 * g0.y + a1 * g1.y;
            wsum += a0 * g0.x + a1 * g1.x;
        }
        if (i < e1) {
            u64 en = sorted[i];
            float2 g = dx[(int)(en & 0x3ffffu)];
            float a = __uint_as_float((unsigned)(en >> 32));
            acc += a * g.y;
            wsum += a * g.x;
        }
    }
    acc += __shfl_xor(acc, 1);
    wsum += __shfl_xor(wsum, 1);
    if (h == 0 && n < N_NODES) {
        float2 d2 = dx[n];
        float dn = d2.x;
        float base0 = dn * acc + dn * d2.y;     // + dn^2 * x[n]
        db0[n] = make_float2(dn, base0);
        s1v[n] = dn * wsum + dn * dn;
    }
}

// layer 1: 2 threads/node edge phase (q[16] partials, shfl_xor combine), then
// 16-lane epilogue: v2 = q@M + c*m2 + cb1 ; h2hat = dinv*(relu(v2)@lw1 + lb1)
// M = lw0@cwr0, m2 = lb0@cwr0 computed block-locally (prep fused). Epilogue
// weight-columns loaded AFTER edge loop to keep edge-phase VGPR low.
__global__ __launch_bounds__(256) void agg1_kernel(const u64* __restrict__ sorted,
                                                   const int* __restrict__ nodeoff,
                                                   const float2* __restrict__ db0,
                                                   const float* __restrict__ s1v,
                                                   const float* __restrict__ cw0,
                                                   const float* __restrict__ cb0,
                                                   const float* __restrict__ lw0,
                                                   const float* __restrict__ lb0,
                                                   const float* __restrict__ cwr0,
                                                   const float* __restrict__ cb1,
                                                   const float* __restrict__ lw1,
                                                   const float* __restrict__ lb1,
                                                   float* __restrict__ h2hat) {
    __shared__ float sq[128 * 20];   // per node: q[16], c, dn, pad2  (10 KB)
    __shared__ float sa2[256];       // wave-local relu scratch
    __shared__ float sM[256];        // M = lw0 @ cwr0
    __shared__ float sm2[16];        // m2 = lb0 @ cwr0
    int t = threadIdx.x;
    int j = t & 15;
    {   // fused prep
        int kk = t >> 4;
        float accM = 0.f;
#pragma unroll
        for (int xx = 0; xx < 16; ++xx) accM += lw0[kk * 16 + xx] * cwr0[xx * 16 + j];
        sM[t] = accM;
        if (t < 16) {
            float a2 = 0.f;
#pragma unroll
            for (int xx = 0; xx < 16; ++xx) a2 += lb0[xx] * cwr0[xx * 16 + t];
            sm2[t] = a2;
        }
    }
    __syncthreads();
    float cwr[16], cbr[16];
#pragma unroll
    for (int k = 0; k < 16; ++k) { cwr[k] = cw0[k]; cbr[k] = cb0[k]; }

    int n = blockIdx.x * 128 + (t >> 1);
    int h = t & 1;
    float q[16];
#pragma unroll
    for (int k = 0; k < 16; ++k) q[k] = 0.f;
    if (n < N_NODES) {
        int e0 = nodeoff[n];
        int e1 = (n < N_NODES - 1) ? nodeoff[n + 1] : N_EDGES;
        int i = e0 + h;
        for (; i + 2 < e1; i += 4) {
            u64 en0 = sorted[i], en1 = sorted[i + 2];
            float2 g0 = db0[(int)(en0 & 0x3ffffu)];
            float2 g1 = db0[(int)(en1 & 0x3ffffu)];
            float a0 = __uint_as_float((unsigned)(en0 >> 32)) * g0.x;  // ea*dinv[s]
            float a1 = __uint_as_float((unsigned)(en1 >> 32)) * g1.x;
#pragma unroll
            for (int k = 0; k < 16; ++k)
                q[k] += a0 * fmaxf(g0.y * cwr[k] + cbr[k], 0.f)
                      + a1 * fmaxf(g1.y * cwr[k] + cbr[k], 0.f);
        }
        if (i < e1) {
            u64 en = sorted[i];
            float2 g = db0[(int)(en & 0x3ffffu)];
            float a = __uint_as_float((unsigned)(en >> 32)) * g.x;
#pragma unroll
            for (int k = 0; k < 16; ++k)
                q[k] += a * fmaxf(g.y * cwr[k] + cbr[k], 0.f);
        }
    }
    // combine halves (lane pairs 2k/2k+1, in-wave)
#pragma unroll
    for (int k = 0; k < 16; ++k) q[k] += __shfl_xor(q[k], 1);
    float dn = 0.f, cval = 0.f;
    if (n < N_NODES) {
        float2 self = db0[n];
        dn = self.x;
        float ds = dn * dn;
#pragma unroll
        for (int k = 0; k < 16; ++k)
            q[k] = dn * q[k] + ds * fmaxf(self.y * cwr[k] + cbr[k], 0.f);
        cval = s1v[n];
    }
    if (h == 0) {
        float* row = sq + (t >> 1) * 20;
#pragma unroll
        for (int k = 0; k < 16; k += 4)
            *(float4*)(row + k) = make_float4(q[k], q[k + 1], q[k + 2], q[k + 3]);
        row[16] = cval;
        row[17] = dn;
    }
    __syncthreads();
    // epilogue weights loaded now (post edge phase — lower edge-phase VGPR)
    float Mc[16], W1c[16];
#pragma unroll
    for (int k = 0; k < 16; ++k) { Mc[k] = sM[k * 16 + j]; W1c[k] = lw1[k * 16 + j]; }
    float m2j = sm2[j], cb1j = cb1[j], lb1j = lb1[j];
    int g = t >> 4;
    float* ar = sa2 + g * 16;
    for (int it = 0; it < 8; ++it) {
        int nl = g * 8 + it;
        const float* r = sq + nl * 20;
        float4 q0 = *(const float4*)(r);
        float4 q1 = *(const float4*)(r + 4);
        float4 q2 = *(const float4*)(r + 8);
        float4 q3 = *(const float4*)(r + 12);
        float c2 = r[16], dn2 = r[17];
        float v2 = c2 * m2j + cb1j;
        v2 += q0.x * Mc[0] + q0.y * Mc[1] + q0.z * Mc[2] + q0.w * Mc[3];
        v2 += q1.x * Mc[4] + q1.y * Mc[5] + q1.z * Mc[6] + q1.w * Mc[7];
        v2 += q2.x * Mc[8] + q2.y * Mc[9] + q2.z * Mc[10] + q2.w * Mc[11];
        v2 += q3.x * Mc[12] + q3.y * Mc[13] + q3.z * Mc[14] + q3.w * Mc[15];
        ar[j] = fmaxf(v2, 0.f);          // wave-local
        float o = lb1j;
#pragma unroll
        for (int k = 0; k < 16; ++k) o += ar[k] * W1c[k];
        int n2 = blockIdx.x * 128 + nl;
        if (n2 < N_NODES) h2hat[(size_t)n2 * 16 + j] = dn2 * o;
    }
}

// layer 2: 16 lanes/group, 4 nodes/group; simple unroll-8 gathers; nontemporal
// loads for the streamed `sorted` (preserve L2 for the 12.8 MB h2hat target);
// wave-local LDS epilogue; writes h3.
__global__ __launch_bounds__(256) void agg2_kernel(const u64* __restrict__ sorted,
                                                   const int* __restrict__ nodeoff,
                                                   const float* __restrict__ h2hat,
                                                   const float* __restrict__ dinv,
                                                   const float* __restrict__ cwr1,
                                                   const float* __restrict__ cb2,
                                                   const float* __restrict__ lw2,
                                                   const float* __restrict__ lb2,
                                                   float* __restrict__ h3) {
    __shared__ float sz[256];   // per (group, j) — wave-local roundtrip
    int t = threadIdx.x, j = t & 15, g = t >> 4;
    float W1c[16], W2c[16];
#pragma unroll
    for (int k = 0; k < 16; ++k) { W1c[k] = cwr1[k * 16 + j]; W2c[k] = lw2[k * 16 + j]; }
    float cb2j = cb2[j], lb2j = lb2[j];
    const float* zr = sz + g * 16;
    int nbase = blockIdx.x * 64 + g * 4;     // 3125 * 64 = 200000 exactly
#pragma unroll
    for (int it = 0; it < 4; ++it) {
        int n = nbase + it;
        int e0 = nodeoff[n];
        int e1 = (n < N_NODES - 1) ? nodeoff[n + 1] : N_EDGES;
        float q = 0.f;
        int i = e0;
        for (; i + 8 <= e1; i += 8) {
            u64 en0 = NTL(sorted + i),     en1 = NTL(sorted + i + 1);
            u64 en2 = NTL(sorted + i + 2), en3 = NTL(sorted + i + 3);
            u64 en4 = NTL(sorted + i + 4), en5 = NTL(sorted + i + 5);
            u64 en6 = NTL(sorted + i + 6), en7 = NTL(sorted + i + 7);
            float g0 = h2hat[(size_t)(en0 & 0x3ffffu) * 16 + j];
            float g1 = h2hat[(size_t)(en1 & 0x3ffffu) * 16 + j];
            float g2 = h2hat[(size_t)(en2 & 0x3ffffu) * 16 + j];
            float g3 = h2hat[(size_t)(en3 & 0x3ffffu) * 16 + j];
            float g4 = h2hat[(size_t)(en4 & 0x3ffffu) * 16 + j];
            float g5 = h2hat[(size_t)(en5 & 0x3ffffu) * 16 + j];
            float g6 = h2hat[(size_t)(en6 & 0x3ffffu) * 16 + j];
            float g7 = h2hat[(size_t)(en7 & 0x3ffffu) * 16 + j];
            q += __uint_as_float((unsigned)(en0 >> 32)) * g0
               + __uint_as_float((unsigned)(en1 >> 32)) * g1
               + __uint_as_float((unsigned)(en2 >> 32)) * g2
               + __uint_as_float((unsigned)(en3 >> 32)) * g3
               + __uint_as_float((unsigned)(en4 >> 32)) * g4
               + __uint_as_float((unsigned)(en5 >> 32)) * g5
               + __uint_as_float((unsigned)(en6 >> 32)) * g6
               + __uint_as_float((unsigned)(en7 >> 32)) * g7;
        }
        for (; i < e1; ++i) {
            u64 en = NTL(sorted + i);
            q += __uint_as_float((unsigned)(en >> 32)) * h2hat[(size_t)(en & 0x3ffffu) * 16 + j];
        }
        float dn = dinv[n];
        float z = dn * (q + h2hat[(size_t)n * 16 + j]);   // + dn^2 * h2[n]
        sz[t] = z;                                        // wave-local
        float v = cb2j;
#pragma unroll
        for (int k = 0; k < 16; ++k) v += zr[k] * W1c[k];
        float a = fmaxf(v, 0.f);
        sz[t] = a;                                        // wave-local overwrite
        float o = lb2j;
#pragma unroll
        for (int k = 0; k < 16; ++k) o += zr[k] * W2c[k];
        h3[(size_t)n * 16 + j] = o;
    }
}

// segmented pooling over sorted batch (~116k global fp atomics total)
#define POOL_RUN 32
__global__ __launch_bounds__(256) void pool_kernel(const float* __restrict__ h,
                                                   const int* __restrict__ batch,
                                                   float* __restrict__ num,
                                                   float* __restrict__ den) {
    int t = threadIdx.x;
    int tg = t >> 4, j = t & 15;
    int n_start = blockIdx.x * (16 * POOL_RUN) + tg * POOL_RUN;
    float accn = 0.f, accd = 0.f;
    int cur = -1;
    for (int k = 0; k < POOL_RUN; ++k) {
        int n = n_start + k;
        if (n >= N_NODES) break;
        int g = batch[n];
        if (g != cur) {
            if (cur >= 0) {
                atomicAdd(&num[cur * HD + j], accn);
                atomicAdd(&den[cur * HD + j], accd);
            }
            cur = g;
            accn = 0.f;
            accd = 0.f;
        }
        float v = h[(size_t)n * HD + j];
        float s = __expf(ALPHA_ * v);
        accn += v * s;
        accd += s;
    }
    if (cur >= 0) {
        atomicAdd(&num[cur * HD + j], accn);
        atomicAdd(&den[cur * HD + j], accd);
    }
}

__global__ __launch_bounds__(64) void final_kernel(const float* __restrict__ num,
                                                   const float* __restrict__ den,
                                                   const float* __restrict__ w1,
                                                   const float* __restrict__ b1,
                                                   const float* __restrict__ w2,
                                                   const float* __restrict__ b2,
                                                   const float* __restrict__ w3,
                                                   const float* __restrict__ b3,
                                                   float* __restrict__ out) {
    int g = blockIdx.x * blockDim.x + threadIdx.x;
    if (g >= N_GRAPHS) return;
    float p[16];
#pragma unroll
    for (int j = 0; j < 16; ++j) p[j] = num[g * HD + j] / den[g * HD + j];
    float t1[16];
#pragma unroll
    for (int j = 0; j < 16; ++j) {
        float acc = b1[j];
#pragma unroll
        for (int k = 0; k < 16; ++k) acc += p[k] * w1[k * 16 + j];
        t1[j] = fmaxf(acc, 0.f);
    }
    float t2[16];
#pragma unroll
    for (int j = 0; j < 16; ++j) {
        float acc = b2[j];
#pragma unroll
        for (int k = 0; k < 16; ++k) acc += t1[k] * w2[k * 16 + j];
        t2[j] = fmaxf(acc, 0.f);
    }
    float o = b3[0];
#pragma unroll
    for (int k = 0; k < 16; ++k) o += t2[k] * w3[k];
    out[g] = o;
}

extern "C" void kernel_launch(void* const* d_in, const int* in_sizes, int n_in,
                              void* d_out, int out_size, void* d_ws, size_t ws_size,
                              hipStream_t stream) {
    const float* x   = (const float*)d_in[0];
    const int*   ei  = (const int*)d_in[1];
    const int*   src = ei;
    const int*   dst = ei + N_EDGES;
    const int*   batch = (const int*)d_in[2];
    const float* ea  = (const float*)d_in[3];
    const float* cw0 = (const float*)d_in[4];
    const float* cwr = (const float*)d_in[5];
    const float* cb  = (const float*)d_in[6];
    const float* lw  = (const float*)d_in[7];
    const float* lb  = (const float*)d_in[8];
    const float* w1  = (const float*)d_in[9];
    const float* b1  = (const float*)d_in[10];
    const float* w2  = (const float*)d_in[11];
    const float* b2  = (const float*)d_in[12];
    const float* w3  = (const float*)d_in[13];
    const float* b3  = (const float*)d_in[14];
    float* out = (float*)d_out;

    // workspace layout (4-byte units) — offsets unchanged (validated)
    float* ws      = (float*)d_ws;
    float* dinv    = ws;                                   // 200000
    float* s1v     = ws + 200000;                          // 200000
    int*   blkhist = (int*)(ws + 400000);                  // reserve 2443750 (uses 152881)
    float2* db0    = (float2*)(ws + 400000);               // aliases blkhist; 400000 floats
    int*   bstart  = blkhist + 2443750;                    // 392 (pad 784)
    int*   nodeoff = bstart + 784;                         // 200000 (pad 200010)
    float* num     = (float*)(nodeoff + 200010);           // 16384
    float* den     = num + 16384;                          // 16384
    float* Mm      = den + 16384;                          // 288 (unused, keeps offsets)
    float2* dx     = (float2*)(Mm + 288);                  // 400000 floats (even offset)
    u64* bucketed  = (u64*)((float*)dx + 400000);          // E u64 (even offset)
    u64* sorted    = bucketed + N_EDGES;                   // E u64
    float* h2hat   = (float*)bucketed;                     // alias: free after sortd
    float* h3      = h2hat + (size_t)N_NODES * HD;         // alias (bucketed region)

    hipMemsetAsync(num, 0, (size_t)2 * N_GRAPHS * HD * sizeof(float), stream);

    // full sort by dst: radix pass 1 (bucket dst>>9), pass 2 (in-bucket 9b dlow + dinv/dx)
    hist_kernel<<<NBLKA, 256, 0, stream>>>(dst, blkhist);
    scanA_kernel<<<NBUCK, 256, 0, stream>>>(blkhist, bstart);
    scanB_kernel<<<1, 256, 0, stream>>>(bstart);
    scatter_kernel<<<NBLKA, 256, 0, stream>>>(src, dst, ea, blkhist, bstart, bucketed);
    sortd_kernel<<<NBUCK, 256, 0, stream>>>(bucketed, bstart, x, sorted, nodeoff, dinv, dx);

    // layer 0 (2 threads/node) -> db0={dinv,base0}, s1
    agg0_kernel<<<1563, 256, 0, stream>>>(sorted, nodeoff, dx, db0, s1v);
    // layer 1 (2 threads/node + fused prep + 2-stage epilogue) -> h2hat
    agg1_kernel<<<1563, 256, 0, stream>>>(sorted, nodeoff, db0, s1v,
                                          cw0, cb, lw, lb,
                                          cwr, cb + 16, lw + 256, lb + 16, h2hat);
    // layer 2 (simple unroll-8 gathers, nontemporal entry stream) -> h3
    agg2_kernel<<<3125, 256, 0, stream>>>(sorted, nodeoff, h2hat, dinv,
                                          cwr + 256, cb + 32, lw + 512, lb + 32, h3);

    pool_kernel<<<(N_NODES + 16 * POOL_RUN - 1) / (16 * POOL_RUN), 256, 0, stream>>>(h3, batch, num, den);
    final_kernel<<<(N_GRAPHS + 63) / 64, 64, 0, stream>>>(num, den, w1, b1, w2, b2, w3, b3, out);
}

// Round 14
// 360.000 us; speedup vs baseline: 1.0715x; 1.0715x over previous
//
#include <hip/hip_runtime.h>

#define N_NODES 200000
#define N_EDGES 3200000
#define N_GRAPHS 1024
#define HD 16
#define ALPHA_ 0.2f

#define BNODES 512                 // nodes per bucket (dst >> 9)
#define NBUCK 391                  // ceil(N_NODES/512)
#define CHUNKA 2048                // edges per pass-A block (small: occupancy for hist/scatter)
#define NBLKA 1563                 // ceil(N_EDGES/2048)
#define PERA 7                     // ceil(NBLKA/256)

typedef unsigned long long u64;

// ---------- radix pass 1: bucket by dst>>9 (int LDS atomics only) ----------
__global__ __launch_bounds__(256) void hist_kernel(const int* __restrict__ dst,
                                                   int* __restrict__ blkhist) {
    __shared__ int hist[NBUCK];
    int t = threadIdx.x;
    for (int i = t; i < NBUCK; i += 256) hist[i] = 0;
    __syncthreads();
    int e0 = blockIdx.x * CHUNKA;
    int e1 = min(e0 + CHUNKA, N_EDGES);
#pragma unroll
    for (int k = 0; k < 2; ++k) {
        int e = e0 + (k << 10) + (t << 2);
        if (e < e1) {   // e, e1 multiples of 4 -> full int4 valid
            int4 d4 = *(const int4*)(dst + e);
            atomicAdd(&hist[d4.x >> 9], 1);
            atomicAdd(&hist[d4.y >> 9], 1);
            atomicAdd(&hist[d4.z >> 9], 1);
            atomicAdd(&hist[d4.w >> 9], 1);
        }
    }
    __syncthreads();
    int* out = blkhist + (size_t)blockIdx.x * NBUCK;
    for (int i = t; i < NBUCK; i += 256) out[i] = hist[i];
}

// column-wise exclusive scan across NBLKA blocks; totals -> bstart
__global__ __launch_bounds__(256) void scanA_kernel(int* __restrict__ blkhist,
                                                    int* __restrict__ bstart) {
    __shared__ int s[256];
    int u = blockIdx.x, t = threadIdx.x;
    int v[PERA];
    int sum = 0;
#pragma unroll
    for (int i = 0; i < PERA; ++i) {
        int j = t * PERA + i;
        v[i] = (j < NBLKA) ? blkhist[(size_t)j * NBUCK + u] : 0;
        sum += v[i];
    }
    s[t] = sum;
    __syncthreads();
    for (int off = 1; off < 256; off <<= 1) {
        int x = (t >= off) ? s[t - off] : 0;
        __syncthreads();
        s[t] += x;
        __syncthreads();
    }
    int run = s[t] - sum;
#pragma unroll
    for (int i = 0; i < PERA; ++i) {
        int j = t * PERA + i;
        if (j < NBLKA) blkhist[(size_t)j * NBUCK + u] = run;
        run += v[i];
    }
    if (t == 255) bstart[u] = s[255];
}

// exclusive scan over bucket totals (single block)
__global__ __launch_bounds__(256) void scanB_kernel(int* __restrict__ bstart) {
    __shared__ int s[256];
    int t = threadIdx.x;
    int v[2];
    int sum = 0;
#pragma unroll
    for (int i = 0; i < 2; ++i) {
        int j = t * 2 + i;
        v[i] = (j < NBUCK) ? bstart[j] : 0;
        sum += v[i];
    }
    s[t] = sum;
    __syncthreads();
    for (int off = 1; off < 256; off <<= 1) {
        int x = (t >= off) ? s[t - off] : 0;
        __syncthreads();
        s[t] += x;
        __syncthreads();
    }
    int run = s[t] - sum;
#pragma unroll
    for (int i = 0; i < 2; ++i) {
        int j = t * 2 + i;
        if (j < NBUCK) bstart[j] = run;
        run += v[i];
    }
    if (t == 255) bstart[NBUCK] = s[255];
}

// entry = (ea:32 | dlow:9 | src:18)
__global__ __launch_bounds__(256) void scatter_kernel(const int* __restrict__ src,
                                                      const int* __restrict__ dst,
                                                      const float* __restrict__ ea,
                                                      const int* __restrict__ blkhist,
                                                      const int* __restrict__ bstart,
                                                      u64* __restrict__ bucketed) {
    __shared__ int cursor[NBUCK];
    int t = threadIdx.x;
    const int* bo = blkhist + (size_t)blockIdx.x * NBUCK;
    for (int i = t; i < NBUCK; i += 256) cursor[i] = bstart[i] + bo[i];
    __syncthreads();
    int e0 = blockIdx.x * CHUNKA;
    int e1 = min(e0 + CHUNKA, N_EDGES);
#pragma unroll
    for (int k = 0; k < 2; ++k) {
        int e = e0 + (k << 10) + (t << 2);
        if (e < e1) {   // full int4/float4 valid (multiples of 4)
            int4   d4 = *(const int4*)(dst + e);
            int4   s4 = *(const int4*)(src + e);
            float4 a4 = *(const float4*)(ea + e);
            int p0 = atomicAdd(&cursor[d4.x >> 9], 1);
            int p1 = atomicAdd(&cursor[d4.y >> 9], 1);
            int p2 = atomicAdd(&cursor[d4.z >> 9], 1);
            int p3 = atomicAdd(&cursor[d4.w >> 9], 1);
            bucketed[p0] = ((u64)__float_as_uint(a4.x) << 32) | (unsigned)(s4.x | ((d4.x & 511) << 18));
            bucketed[p1] = ((u64)__float_as_uint(a4.y) << 32) | (unsigned)(s4.y | ((d4.y & 511) << 18));
            bucketed[p2] = ((u64)__float_as_uint(a4.z) << 32) | (unsigned)(s4.z | ((d4.z & 511) << 18));
            bucketed[p3] = ((u64)__float_as_uint(a4.w) << 32) | (unsigned)(s4.w | ((d4.w & 511) << 18));
        }
    }
}

// radix pass 2: in-bucket counting sort by dlow (9b, int LDS atomics) + fused
// per-node weighted degree -> dinv, dx = {dinv, dinv*x}.
// 512 threads/block (1 node/thread) — 8 waves/block for occupancy.
__global__ __launch_bounds__(512) void sortd_kernel(const u64* __restrict__ bucketed,
                                                    const int* __restrict__ bstart,
                                                    const float* __restrict__ x,
                                                    u64* __restrict__ sorted,
                                                    int* __restrict__ nodeoff,
                                                    float* __restrict__ dinv,
                                                    float2* __restrict__ dx) {
    __shared__ int hist[512];
    __shared__ int s[512];
    __shared__ int cur[512];
    int u = blockIdx.x, t = threadIdx.x;
    hist[t] = 0;
    __syncthreads();
    int b0 = bstart[u], b1 = bstart[u + 1];
    for (int i = b0 + t; i < b1; i += 512)
        atomicAdd(&hist[(int)((bucketed[i] >> 18) & 511u)], 1);
    __syncthreads();
    int c = hist[t];
    s[t] = c;
    __syncthreads();
    for (int off = 1; off < 512; off <<= 1) {
        int v = (t >= off) ? s[t - off] : 0;
        __syncthreads();
        s[t] += v;
        __syncthreads();
    }
    int loc = b0 + s[t] - c;   // exclusive
    cur[t] = loc;
    int n = u * BNODES + t;
    if (n < N_NODES) nodeoff[n] = loc;
    __syncthreads();
    for (int i = b0 + t; i < b1; i += 512) {
        u64 ent = bucketed[i];
        int pos = atomicAdd(&cur[(int)((ent >> 18) & 511u)], 1);
        sorted[pos] = ent;
    }
    __syncthreads();
    // per-node serial weighted degree over own contiguous range (L1/L2-hot)
    if (n < N_NODES) {
        float sum = 0.f;
        for (int k = 0; k < c; ++k)
            sum += __uint_as_float((unsigned)(sorted[loc + k] >> 32));
        float dn = rsqrtf(sum + 1.0f);
        dinv[n] = dn;
        dx[n] = make_float2(dn, dn * x[n]);
    }
}

// layer 0: 2 threads/node (stride-2 halves, shfl_xor combine)
__global__ __launch_bounds__(256) void agg0_kernel(const u64* __restrict__ sorted,
                                                   const int* __restrict__ nodeoff,
                                                   const float2* __restrict__ dx,
                                                   float2* __restrict__ db0,
                                                   float* __restrict__ s1v) {
    int t = threadIdx.x;
    int n = blockIdx.x * 128 + (t >> 1);
    int h = t & 1;
    float acc = 0.f, wsum = 0.f;
    if (n < N_NODES) {
        int e0 = nodeoff[n];
        int e1 = (n < N_NODES - 1) ? nodeoff[n + 1] : N_EDGES;
        int i = e0 + h;
        for (; i + 2 < e1; i += 4) {
            u64 en0 = sorted[i], en1 = sorted[i + 2];
            float2 g0 = dx[(int)(en0 & 0x3ffffu)];
            float2 g1 = dx[(int)(en1 & 0x3ffffu)];
            float a0 = __uint_as_float((unsigned)(en0 >> 32));
            float a1 = __uint_as_float((unsigned)(en1 >> 32));
            acc += a0 * g0.y + a1 * g1.y;
            wsum += a0 * g0.x + a1 * g1.x;
        }
        if (i < e1) {
            u64 en = sorted[i];
            float2 g = dx[(int)(en & 0x3ffffu)];
            float a = __uint_as_float((unsigned)(en >> 32));
            acc += a * g.y;
            wsum += a * g.x;
        }
    }
    acc += __shfl_xor(acc, 1);
    wsum += __shfl_xor(wsum, 1);
    if (h == 0 && n < N_NODES) {
        float2 d2 = dx[n];
        float dn = d2.x;
        float base0 = dn * acc + dn * d2.y;     // + dn^2 * x[n]
        db0[n] = make_float2(dn, base0);
        s1v[n] = dn * wsum + dn * dn;
    }
}

// layer 1: 2 threads/node edge phase (q[16] partials, shfl_xor combine), then
// 16-lane epilogue: v2 = q@M + c*m2 + cb1 ; h2hat = dinv*(relu(v2)@lw1 + lb1)
__global__ __launch_bounds__(256) void agg1_kernel(const u64* __restrict__ sorted,
                                                   const int* __restrict__ nodeoff,
                                                   const float2* __restrict__ db0,
                                                   const float* __restrict__ s1v,
                                                   const float* __restrict__ cw0,
                                                   const float* __restrict__ cb0,
                                                   const float* __restrict__ lw0,
                                                   const float* __restrict__ lb0,
                                                   const float* __restrict__ cwr0,
                                                   const float* __restrict__ cb1,
                                                   const float* __restrict__ lw1,
                                                   const float* __restrict__ lb1,
                                                   float* __restrict__ h2hat) {
    __shared__ float sq[128 * 20];   // per node: q[16], c, dn, pad2  (10 KB)
    __shared__ float sa2[256];       // wave-local relu scratch
    __shared__ float sM[256];        // M = lw0 @ cwr0
    __shared__ float sm2[16];        // m2 = lb0 @ cwr0
    int t = threadIdx.x;
    int j = t & 15;
    {   // fused prep
        int kk = t >> 4;
        float accM = 0.f;
#pragma unroll
        for (int xx = 0; xx < 16; ++xx) accM += lw0[kk * 16 + xx] * cwr0[xx * 16 + j];
        sM[t] = accM;
        if (t < 16) {
            float a2 = 0.f;
#pragma unroll
            for (int xx = 0; xx < 16; ++xx) a2 += lb0[xx] * cwr0[xx * 16 + t];
            sm2[t] = a2;
        }
    }
    __syncthreads();
    float cwr[16], cbr[16];
#pragma unroll
    for (int k = 0; k < 16; ++k) { cwr[k] = cw0[k]; cbr[k] = cb0[k]; }

    int n = blockIdx.x * 128 + (t >> 1);
    int h = t & 1;
    float q[16];
#pragma unroll
    for (int k = 0; k < 16; ++k) q[k] = 0.f;
    if (n < N_NODES) {
        int e0 = nodeoff[n];
        int e1 = (n < N_NODES - 1) ? nodeoff[n + 1] : N_EDGES;
        int i = e0 + h;
        for (; i + 2 < e1; i += 4) {
            u64 en0 = sorted[i], en1 = sorted[i + 2];
            float2 g0 = db0[(int)(en0 & 0x3ffffu)];
            float2 g1 = db0[(int)(en1 & 0x3ffffu)];
            float a0 = __uint_as_float((unsigned)(en0 >> 32)) * g0.x;  // ea*dinv[s]
            float a1 = __uint_as_float((unsigned)(en1 >> 32)) * g1.x;
#pragma unroll
            for (int k = 0; k < 16; ++k)
                q[k] += a0 * fmaxf(g0.y * cwr[k] + cbr[k], 0.f)
                      + a1 * fmaxf(g1.y * cwr[k] + cbr[k], 0.f);
        }
        if (i < e1) {
            u64 en = sorted[i];
            float2 g = db0[(int)(en & 0x3ffffu)];
            float a = __uint_as_float((unsigned)(en >> 32)) * g.x;
#pragma unroll
            for (int k = 0; k < 16; ++k)
                q[k] += a * fmaxf(g.y * cwr[k] + cbr[k], 0.f);
        }
    }
    // combine halves (lane pairs 2k/2k+1, in-wave)
#pragma unroll
    for (int k = 0; k < 16; ++k) q[k] += __shfl_xor(q[k], 1);
    float dn = 0.f, cval = 0.f;
    if (n < N_NODES) {
        float2 self = db0[n];
        dn = self.x;
        float ds = dn * dn;
#pragma unroll
        for (int k = 0; k < 16; ++k)
            q[k] = dn * q[k] + ds * fmaxf(self.y * cwr[k] + cbr[k], 0.f);
        cval = s1v[n];
    }
    if (h == 0) {
        float* row = sq + (t >> 1) * 20;
#pragma unroll
        for (int k = 0; k < 16; k += 4)
            *(float4*)(row + k) = make_float4(q[k], q[k + 1], q[k + 2], q[k + 3]);
        row[16] = cval;
        row[17] = dn;
    }
    __syncthreads();
    // epilogue weights loaded post edge phase (lower edge-phase VGPR)
    float Mc[16], W1c[16];
#pragma unroll
    for (int k = 0; k < 16; ++k) { Mc[k] = sM[k * 16 + j]; W1c[k] = lw1[k * 16 + j]; }
    float m2j = sm2[j], cb1j = cb1[j], lb1j = lb1[j];
    int g = t >> 4;
    float* ar = sa2 + g * 16;
    for (int it = 0; it < 8; ++it) {
        int nl = g * 8 + it;
        const float* r = sq + nl * 20;
        float4 q0 = *(const float4*)(r);
        float4 q1 = *(const float4*)(r + 4);
        float4 q2 = *(const float4*)(r + 8);
        float4 q3 = *(const float4*)(r + 12);
        float c2 = r[16], dn2 = r[17];
        float v2 = c2 * m2j + cb1j;
        v2 += q0.x * Mc[0] + q0.y * Mc[1] + q0.z * Mc[2] + q0.w * Mc[3];
        v2 += q1.x * Mc[4] + q1.y * Mc[5] + q1.z * Mc[6] + q1.w * Mc[7];
        v2 += q2.x * Mc[8] + q2.y * Mc[9] + q2.z * Mc[10] + q2.w * Mc[11];
        v2 += q3.x * Mc[12] + q3.y * Mc[13] + q3.z * Mc[14] + q3.w * Mc[15];
        ar[j] = fmaxf(v2, 0.f);          // wave-local
        float o = lb1j;
#pragma unroll
        for (int k = 0; k < 16; ++k) o += ar[k] * W1c[k];
        int n2 = blockIdx.x * 128 + nl;
        if (n2 < N_NODES) h2hat[(size_t)n2 * 16 + j] = dn2 * o;
    }
}

// layer 2: 16 lanes/group, 4 nodes/group; simple unroll-8 plain gathers
// (NT loads regressed — R13; explicit dbuf regressed — R10; keep 36-VGPR form);
// wave-local LDS epilogue; writes h3.
__global__ __launch_bounds__(256) void agg2_kernel(const u64* __restrict__ sorted,
                                                   const int* __restrict__ nodeoff,
                                                   const float* __restrict__ h2hat,
                                                   const float* __restrict__ dinv,
                                                   const float* __restrict__ cwr1,
                                                   const float* __restrict__ cb2,
                                                   const float* __restrict__ lw2,
                                                   const float* __restrict__ lb2,
                                                   float* __restrict__ h3) {
    __shared__ float sz[256];   // per (group, j) — wave-local roundtrip
    int t = threadIdx.x, j = t & 15, g = t >> 4;
    float W1c[16], W2c[16];
#pragma unroll
    for (int k = 0; k < 16; ++k) { W1c[k] = cwr1[k * 16 + j]; W2c[k] = lw2[k * 16 + j]; }
    float cb2j = cb2[j], lb2j = lb2[j];
    const float* zr = sz + g * 16;
    int nbase = blockIdx.x * 64 + g * 4;     // 3125 * 64 = 200000 exactly
#pragma unroll
    for (int it = 0; it < 4; ++it) {
        int n = nbase + it;
        int e0 = nodeoff[n];
        int e1 = (n < N_NODES - 1) ? nodeoff[n + 1] : N_EDGES;
        float q = 0.f;
        int i = e0;
        for (; i + 8 <= e1; i += 8) {
            u64 en0 = sorted[i],     en1 = sorted[i + 1], en2 = sorted[i + 2], en3 = sorted[i + 3];
            u64 en4 = sorted[i + 4], en5 = sorted[i + 5], en6 = sorted[i + 6], en7 = sorted[i + 7];
            float g0 = h2hat[(size_t)(en0 & 0x3ffffu) * 16 + j];
            float g1 = h2hat[(size_t)(en1 & 0x3ffffu) * 16 + j];
            float g2 = h2hat[(size_t)(en2 & 0x3ffffu) * 16 + j];
            float g3 = h2hat[(size_t)(en3 & 0x3ffffu) * 16 + j];
            float g4 = h2hat[(size_t)(en4 & 0x3ffffu) * 16 + j];
            float g5 = h2hat[(size_t)(en5 & 0x3ffffu) * 16 + j];
            float g6 = h2hat[(size_t)(en6 & 0x3ffffu) * 16 + j];
            float g7 = h2hat[(size_t)(en7 & 0x3ffffu) * 16 + j];
            q += __uint_as_float((unsigned)(en0 >> 32)) * g0
               + __uint_as_float((unsigned)(en1 >> 32)) * g1
               + __uint_as_float((unsigned)(en2 >> 32)) * g2
               + __uint_as_float((unsigned)(en3 >> 32)) * g3
               + __uint_as_float((unsigned)(en4 >> 32)) * g4
               + __uint_as_float((unsigned)(en5 >> 32)) * g5
               + __uint_as_float((unsigned)(en6 >> 32)) * g6
               + __uint_as_float((unsigned)(en7 >> 32)) * g7;
        }
        for (; i < e1; ++i) {
            u64 en = sorted[i];
            q += __uint_as_float((unsigned)(en >> 32)) * h2hat[(size_t)(en & 0x3ffffu) * 16 + j];
        }
        float dn = dinv[n];
        float z = dn * (q + h2hat[(size_t)n * 16 + j]);   // + dn^2 * h2[n]
        sz[t] = z;                                        // wave-local
        float v = cb2j;
#pragma unroll
        for (int k = 0; k < 16; ++k) v += zr[k] * W1c[k];
        float a = fmaxf(v, 0.f);
        sz[t] = a;                                        // wave-local overwrite
        float o = lb2j;
#pragma unroll
        for (int k = 0; k < 16; ++k) o += zr[k] * W2c[k];
        h3[(size_t)n * 16 + j] = o;
    }
}

// segmented pooling over sorted batch (~116k global fp atomics total)
#define POOL_RUN 32
__global__ __launch_bounds__(256) void pool_kernel(const float* __restrict__ h,
                                                   const int* __restrict__ batch,
                                                   float* __restrict__ num,
                                                   float* __restrict__ den) {
    int t = threadIdx.x;
    int tg = t >> 4, j = t & 15;
    int n_start = blockIdx.x * (16 * POOL_RUN) + tg * POOL_RUN;
    float accn = 0.f, accd = 0.f;
    int cur = -1;
    for (int k = 0; k < POOL_RUN; ++k) {
        int n = n_start + k;
        if (n >= N_NODES) break;
        int g = batch[n];
        if (g != cur) {
            if (cur >= 0) {
                atomicAdd(&num[cur * HD + j], accn);
                atomicAdd(&den[cur * HD + j], accd);
            }
            cur = g;
            accn = 0.f;
            accd = 0.f;
        }
        float v = h[(size_t)n * HD + j];
        float s = __expf(ALPHA_ * v);
        accn += v * s;
        accd += s;
    }
    if (cur >= 0) {
        atomicAdd(&num[cur * HD + j], accn);
        atomicAdd(&den[cur * HD + j], accd);
    }
}

__global__ __launch_bounds__(64) void final_kernel(const float* __restrict__ num,
                                                   const float* __restrict__ den,
                                                   const float* __restrict__ w1,
                                                   const float* __restrict__ b1,
                                                   const float* __restrict__ w2,
                                                   const float* __restrict__ b2,
                                                   const float* __restrict__ w3,
                                                   const float* __restrict__ b3,
                                                   float* __restrict__ out) {
    int g = blockIdx.x * blockDim.x + threadIdx.x;
    if (g >= N_GRAPHS) return;
    float p[16];
#pragma unroll
    for (int j = 0; j < 16; ++j) p[j] = num[g * HD + j] / den[g * HD + j];
    float t1[16];
#pragma unroll
    for (int j = 0; j < 16; ++j) {
        float acc = b1[j];
#pragma unroll
        for (int k = 0; k < 16; ++k) acc += p[k] * w1[k * 16 + j];
        t1[j] = fmaxf(acc, 0.f);
    }
    float t2[16];
#pragma unroll
    for (int j = 0; j < 16; ++j) {
        float acc = b2[j];
#pragma unroll
        for (int k = 0; k < 16; ++k) acc += t1[k] * w2[k * 16 + j];
        t2[j] = fmaxf(acc, 0.f);
    }
    float o = b3[0];
#pragma unroll
    for (int k = 0; k < 16; ++k) o += t2[k] * w3[k];
    out[g] = o;
}

extern "C" void kernel_launch(void* const* d_in, const int* in_sizes, int n_in,
                              void* d_out, int out_size, void* d_ws, size_t ws_size,
                              hipStream_t stream) {
    const float* x   = (const float*)d_in[0];
    const int*   ei  = (const int*)d_in[1];
    const int*   src = ei;
    const int*   dst = ei + N_EDGES;
    const int*   batch = (const int*)d_in[2];
    const float* ea  = (const float*)d_in[3];
    const float* cw0 = (const float*)d_in[4];
    const float* cwr = (const float*)d_in[5];
    const float* cb  = (const float*)d_in[6];
    const float* lw  = (const float*)d_in[7];
    const float* lb  = (const float*)d_in[8];
    const float* w1  = (const float*)d_in[9];
    const float* b1  = (const float*)d_in[10];
    const float* w2  = (const float*)d_in[11];
    const float* b2  = (const float*)d_in[12];
    const float* w3  = (const float*)d_in[13];
    const float* b3  = (const float*)d_in[14];
    float* out = (float*)d_out;

    // workspace layout (4-byte units) — blkhist reserve covers NBLKA*NBUCK = 611133
    float* ws      = (float*)d_ws;
    float* dinv    = ws;                                   // 200000
    float* s1v     = ws + 200000;                          // 200000
    int*   blkhist = (int*)(ws + 400000);                  // reserve 2443750 (uses 611133)
    float2* db0    = (float2*)(ws + 400000);               // aliases blkhist; 400000 floats
    int*   bstart  = blkhist + 2443750;                    // 392 (pad 784)
    int*   nodeoff = bstart + 784;                         // 200000 (pad 200010)
    float* num     = (float*)(nodeoff + 200010);           // 16384
    float* den     = num + 16384;                          // 16384
    float* Mm      = den + 16384;                          // 288 (unused, keeps offsets)
    float2* dx     = (float2*)(Mm + 288);                  // 400000 floats (even offset)
    u64* bucketed  = (u64*)((float*)dx + 400000);          // E u64 (even offset)
    u64* sorted    = bucketed + N_EDGES;                   // E u64
    float* h2hat   = (float*)bucketed;                     // alias: free after sortd
    float* h3      = h2hat + (size_t)N_NODES * HD;         // alias (bucketed region)

    hipMemsetAsync(num, 0, (size_t)2 * N_GRAPHS * HD * sizeof(float), stream);

    // full sort by dst: radix pass 1 (bucket dst>>9), pass 2 (in-bucket 9b dlow + dinv/dx)
    hist_kernel<<<NBLKA, 256, 0, stream>>>(dst, blkhist);
    scanA_kernel<<<NBUCK, 256, 0, stream>>>(blkhist, bstart);
    scanB_kernel<<<1, 256, 0, stream>>>(bstart);
    scatter_kernel<<<NBLKA, 256, 0, stream>>>(src, dst, ea, blkhist, bstart, bucketed);
    sortd_kernel<<<NBUCK, 512, 0, stream>>>(bucketed, bstart, x, sorted, nodeoff, dinv, dx);

    // layer 0 (2 threads/node) -> db0={dinv,base0}, s1
    agg0_kernel<<<1563, 256, 0, stream>>>(sorted, nodeoff, dx, db0, s1v);
    // layer 1 (2 threads/node + fused prep + 2-stage epilogue) -> h2hat
    agg1_kernel<<<1563, 256, 0, stream>>>(sorted, nodeoff, db0, s1v,
                                          cw0, cb, lw, lb,
                                          cwr, cb + 16, lw + 256, lb + 16, h2hat);
    // layer 2 (simple unroll-8 gathers) -> h3
    agg2_kernel<<<3125, 256, 0, stream>>>(sorted, nodeoff, h2hat, dinv,
                                          cwr + 256, cb + 32, lw + 512, lb + 32, h3);

    pool_kernel<<<(N_NODES + 16 * POOL_RUN - 1) / (16 * POOL_RUN), 256, 0, stream>>>(h3, batch, num, den);
    final_kernel<<<(N_GRAPHS + 63) / 64, 64, 0, stream>>>(num, den, w1, b1, w2, b2, w3, b3, out);
}

// Round 15
// 358.057 us; speedup vs baseline: 1.0774x; 1.0054x over previous
//
#include <hip/hip_runtime.h>

#define N_NODES 200000
#define N_EDGES 3200000
#define N_GRAPHS 1024
#define HD 16
#define ALPHA_ 0.2f

#define BNODES 512                 // nodes per bucket (dst >> 9)
#define NBUCK 391                  // ceil(N_NODES/512)
#define CHUNKA 2048                // edges per pass-A block (small: occupancy for hist/scatter)
#define NBLKA 1563                 // ceil(N_EDGES/2048)
#define NBLKA_PAD 1568             // padded row length for bucket-major blkhist
#define PERA 7                     // ceil(NBLKA/256)

typedef unsigned long long u64;

// ---------- radix pass 1: bucket by dst>>9 (int LDS atomics only) ----------
// blkhist is BUCKET-MAJOR: blkhist[u * NBLKA_PAD + j]  (coalesced scanA)
__global__ __launch_bounds__(256) void hist_kernel(const int* __restrict__ dst,
                                                   int* __restrict__ blkhist) {
    __shared__ int hist[NBUCK];
    int t = threadIdx.x;
    for (int i = t; i < NBUCK; i += 256) hist[i] = 0;
    __syncthreads();
    int e0 = blockIdx.x * CHUNKA;
    int e1 = min(e0 + CHUNKA, N_EDGES);
#pragma unroll
    for (int k = 0; k < 2; ++k) {
        int e = e0 + (k << 10) + (t << 2);
        if (e < e1) {   // e, e1 multiples of 4 -> full int4 valid
            int4 d4 = *(const int4*)(dst + e);
            atomicAdd(&hist[d4.x >> 9], 1);
            atomicAdd(&hist[d4.y >> 9], 1);
            atomicAdd(&hist[d4.z >> 9], 1);
            atomicAdd(&hist[d4.w >> 9], 1);
        }
    }
    __syncthreads();
    // scattered plain stores (write-back L2 absorbs; no atomics)
    for (int u = t; u < NBUCK; u += 256)
        blkhist[(size_t)u * NBLKA_PAD + blockIdx.x] = hist[u];
}

// per-bucket exclusive scan across blocks — now fully coalesced (bucket-major)
__global__ __launch_bounds__(256) void scanA_kernel(int* __restrict__ blkhist,
                                                    int* __restrict__ bstart) {
    __shared__ int s[256];
    int u = blockIdx.x, t = threadIdx.x;
    int* row = blkhist + (size_t)u * NBLKA_PAD;
    int v[PERA];
    int sum = 0;
#pragma unroll
    for (int i = 0; i < PERA; ++i) {
        int j = t * PERA + i;
        v[i] = (j < NBLKA) ? row[j] : 0;
        sum += v[i];
    }
    s[t] = sum;
    __syncthreads();
    for (int off = 1; off < 256; off <<= 1) {
        int x = (t >= off) ? s[t - off] : 0;
        __syncthreads();
        s[t] += x;
        __syncthreads();
    }
    int run = s[t] - sum;
#pragma unroll
    for (int i = 0; i < PERA; ++i) {
        int j = t * PERA + i;
        if (j < NBLKA) row[j] = run;
        run += v[i];
    }
    if (t == 255) bstart[u] = s[255];
}

// exclusive scan over bucket totals (single block)
__global__ __launch_bounds__(256) void scanB_kernel(int* __restrict__ bstart) {
    __shared__ int s[256];
    int t = threadIdx.x;
    int v[2];
    int sum = 0;
#pragma unroll
    for (int i = 0; i < 2; ++i) {
        int j = t * 2 + i;
        v[i] = (j < NBUCK) ? bstart[j] : 0;
        sum += v[i];
    }
    s[t] = sum;
    __syncthreads();
    for (int off = 1; off < 256; off <<= 1) {
        int x = (t >= off) ? s[t - off] : 0;
        __syncthreads();
        s[t] += x;
        __syncthreads();
    }
    int run = s[t] - sum;
#pragma unroll
    for (int i = 0; i < 2; ++i) {
        int j = t * 2 + i;
        if (j < NBUCK) bstart[j] = run;
        run += v[i];
    }
    if (t == 255) bstart[NBUCK] = s[255];
}

// entry = (ea:32 | dlow:9 | src:18)
__global__ __launch_bounds__(256) void scatter_kernel(const int* __restrict__ src,
                                                      const int* __restrict__ dst,
                                                      const float* __restrict__ ea,
                                                      const int* __restrict__ blkhist,
                                                      const int* __restrict__ bstart,
                                                      u64* __restrict__ bucketed) {
    __shared__ int cursor[NBUCK];
    int t = threadIdx.x;
    for (int u = t; u < NBUCK; u += 256)
        cursor[u] = bstart[u] + blkhist[(size_t)u * NBLKA_PAD + blockIdx.x];
    __syncthreads();
    int e0 = blockIdx.x * CHUNKA;
    int e1 = min(e0 + CHUNKA, N_EDGES);
#pragma unroll
    for (int k = 0; k < 2; ++k) {
        int e = e0 + (k << 10) + (t << 2);
        if (e < e1) {   // full int4/float4 valid (multiples of 4)
            int4   d4 = *(const int4*)(dst + e);
            int4   s4 = *(const int4*)(src + e);
            float4 a4 = *(const float4*)(ea + e);
            int p0 = atomicAdd(&cursor[d4.x >> 9], 1);
            int p1 = atomicAdd(&cursor[d4.y >> 9], 1);
            int p2 = atomicAdd(&cursor[d4.z >> 9], 1);
            int p3 = atomicAdd(&cursor[d4.w >> 9], 1);
            bucketed[p0] = ((u64)__float_as_uint(a4.x) << 32) | (unsigned)(s4.x | ((d4.x & 511) << 18));
            bucketed[p1] = ((u64)__float_as_uint(a4.y) << 32) | (unsigned)(s4.y | ((d4.y & 511) << 18));
            bucketed[p2] = ((u64)__float_as_uint(a4.z) << 32) | (unsigned)(s4.z | ((d4.z & 511) << 18));
            bucketed[p3] = ((u64)__float_as_uint(a4.w) << 32) | (unsigned)(s4.w | ((d4.w & 511) << 18));
        }
    }
}

// radix pass 2: in-bucket counting sort by dlow (9b, int LDS atomics) + fused
// per-node weighted degree -> dinv, dx = {dinv, dinv*x}.
// 1024 threads/block (16 waves) — 391 blocks = 1.5/CU, TLP for scattered reads.
__global__ __launch_bounds__(1024) void sortd_kernel(const u64* __restrict__ bucketed,
                                                     const int* __restrict__ bstart,
                                                     const float* __restrict__ x,
                                                     u64* __restrict__ sorted,
                                                     int* __restrict__ nodeoff,
                                                     float* __restrict__ dinv,
                                                     float2* __restrict__ dx) {
    __shared__ int hist[512];
    __shared__ int s[512];
    __shared__ int cur[512];
    int u = blockIdx.x, t = threadIdx.x;
    if (t < 512) hist[t] = 0;
    __syncthreads();
    int b0 = bstart[u], b1 = bstart[u + 1];
    for (int i = b0 + t; i < b1; i += 1024)
        atomicAdd(&hist[(int)((bucketed[i] >> 18) & 511u)], 1);
    __syncthreads();
    int c = (t < 512) ? hist[t] : 0;
    if (t < 512) s[t] = c;
    __syncthreads();
    for (int off = 1; off < 512; off <<= 1) {
        int v = (t >= off && t < 512) ? s[t - off] : 0;
        __syncthreads();
        if (t < 512) s[t] += v;
        __syncthreads();
    }
    int loc = 0;
    if (t < 512) {
        loc = b0 + s[t] - c;   // exclusive
        cur[t] = loc;
        int n = u * BNODES + t;
        if (n < N_NODES) nodeoff[n] = loc;
    }
    __syncthreads();
    for (int i = b0 + t; i < b1; i += 1024) {
        u64 ent = bucketed[i];
        int pos = atomicAdd(&cur[(int)((ent >> 18) & 511u)], 1);
        sorted[pos] = ent;
    }
    __syncthreads();
    // per-node serial weighted degree over own contiguous range (L1/L2-hot)
    if (t < 512) {
        int n = u * BNODES + t;
        if (n < N_NODES) {
            float sum = 0.f;
            for (int k = 0; k < c; ++k)
                sum += __uint_as_float((unsigned)(sorted[loc + k] >> 32));
            float dn = rsqrtf(sum + 1.0f);
            dinv[n] = dn;
            dx[n] = make_float2(dn, dn * x[n]);
        }
    }
}

// layer 0: 2 threads/node (stride-2 halves, shfl_xor combine)
__global__ __launch_bounds__(256) void agg0_kernel(const u64* __restrict__ sorted,
                                                   const int* __restrict__ nodeoff,
                                                   const float2* __restrict__ dx,
                                                   float2* __restrict__ db0,
                                                   float* __restrict__ s1v) {
    int t = threadIdx.x;
    int n = blockIdx.x * 128 + (t >> 1);
    int h = t & 1;
    float acc = 0.f, wsum = 0.f;
    if (n < N_NODES) {
        int e0 = nodeoff[n];
        int e1 = (n < N_NODES - 1) ? nodeoff[n + 1] : N_EDGES;
        int i = e0 + h;
        for (; i + 2 < e1; i += 4) {
            u64 en0 = sorted[i], en1 = sorted[i + 2];
            float2 g0 = dx[(int)(en0 & 0x3ffffu)];
            float2 g1 = dx[(int)(en1 & 0x3ffffu)];
            float a0 = __uint_as_float((unsigned)(en0 >> 32));
            float a1 = __uint_as_float((unsigned)(en1 >> 32));
            acc += a0 * g0.y + a1 * g1.y;
            wsum += a0 * g0.x + a1 * g1.x;
        }
        if (i < e1) {
            u64 en = sorted[i];
            float2 g = dx[(int)(en & 0x3ffffu)];
            float a = __uint_as_float((unsigned)(en >> 32));
            acc += a * g.y;
            wsum += a * g.x;
        }
    }
    acc += __shfl_xor(acc, 1);
    wsum += __shfl_xor(wsum, 1);
    if (h == 0 && n < N_NODES) {
        float2 d2 = dx[n];
        float dn = d2.x;
        float base0 = dn * acc + dn * d2.y;     // + dn^2 * x[n]
        db0[n] = make_float2(dn, base0);
        s1v[n] = dn * wsum + dn * dn;
    }
}

// layer 1: 2 threads/node edge phase (q[16] partials, shfl_xor combine), then
// 16-lane epilogue: v2 = q@M + c*m2 + cb1 ; h2hat = dinv*(relu(v2)@lw1 + lb1)
__global__ __launch_bounds__(256) void agg1_kernel(const u64* __restrict__ sorted,
                                                   const int* __restrict__ nodeoff,
                                                   const float2* __restrict__ db0,
                                                   const float* __restrict__ s1v,
                                                   const float* __restrict__ cw0,
                                                   const float* __restrict__ cb0,
                                                   const float* __restrict__ lw0,
                                                   const float* __restrict__ lb0,
                                                   const float* __restrict__ cwr0,
                                                   const float* __restrict__ cb1,
                                                   const float* __restrict__ lw1,
                                                   const float* __restrict__ lb1,
                                                   float* __restrict__ h2hat) {
    __shared__ float sq[128 * 20];   // per node: q[16], c, dn, pad2  (10 KB)
    __shared__ float sa2[256];       // wave-local relu scratch
    __shared__ float sM[256];        // M = lw0 @ cwr0
    __shared__ float sm2[16];        // m2 = lb0 @ cwr0
    int t = threadIdx.x;
    int j = t & 15;
    {   // fused prep
        int kk = t >> 4;
        float accM = 0.f;
#pragma unroll
        for (int xx = 0; xx < 16; ++xx) accM += lw0[kk * 16 + xx] * cwr0[xx * 16 + j];
        sM[t] = accM;
        if (t < 16) {
            float a2 = 0.f;
#pragma unroll
            for (int xx = 0; xx < 16; ++xx) a2 += lb0[xx] * cwr0[xx * 16 + t];
            sm2[t] = a2;
        }
    }
    __syncthreads();
    float cwr[16], cbr[16];
#pragma unroll
    for (int k = 0; k < 16; ++k) { cwr[k] = cw0[k]; cbr[k] = cb0[k]; }

    int n = blockIdx.x * 128 + (t >> 1);
    int h = t & 1;
    float q[16];
#pragma unroll
    for (int k = 0; k < 16; ++k) q[k] = 0.f;
    if (n < N_NODES) {
        int e0 = nodeoff[n];
        int e1 = (n < N_NODES - 1) ? nodeoff[n + 1] : N_EDGES;
        int i = e0 + h;
        for (; i + 2 < e1; i += 4) {
            u64 en0 = sorted[i], en1 = sorted[i + 2];
            float2 g0 = db0[(int)(en0 & 0x3ffffu)];
            float2 g1 = db0[(int)(en1 & 0x3ffffu)];
            float a0 = __uint_as_float((unsigned)(en0 >> 32)) * g0.x;  // ea*dinv[s]
            float a1 = __uint_as_float((unsigned)(en1 >> 32)) * g1.x;
#pragma unroll
            for (int k = 0; k < 16; ++k)
                q[k] += a0 * fmaxf(g0.y * cwr[k] + cbr[k], 0.f)
                      + a1 * fmaxf(g1.y * cwr[k] + cbr[k], 0.f);
        }
        if (i < e1) {
            u64 en = sorted[i];
            float2 g = db0[(int)(en & 0x3ffffu)];
            float a = __uint_as_float((unsigned)(en >> 32)) * g.x;
#pragma unroll
            for (int k = 0; k < 16; ++k)
                q[k] += a * fmaxf(g.y * cwr[k] + cbr[k], 0.f);
        }
    }
    // combine halves (lane pairs 2k/2k+1, in-wave)
#pragma unroll
    for (int k = 0; k < 16; ++k) q[k] += __shfl_xor(q[k], 1);
    float dn = 0.f, cval = 0.f;
    if (n < N_NODES) {
        float2 self = db0[n];
        dn = self.x;
        float ds = dn * dn;
#pragma unroll
        for (int k = 0; k < 16; ++k)
            q[k] = dn * q[k] + ds * fmaxf(self.y * cwr[k] + cbr[k], 0.f);
        cval = s1v[n];
    }
    if (h == 0) {
        float* row = sq + (t >> 1) * 20;
#pragma unroll
        for (int k = 0; k < 16; k += 4)
            *(float4*)(row + k) = make_float4(q[k], q[k + 1], q[k + 2], q[k + 3]);
        row[16] = cval;
        row[17] = dn;
    }
    __syncthreads();
    // epilogue weights loaded post edge phase (lower edge-phase VGPR)
    float Mc[16], W1c[16];
#pragma unroll
    for (int k = 0; k < 16; ++k) { Mc[k] = sM[k * 16 + j]; W1c[k] = lw1[k * 16 + j]; }
    float m2j = sm2[j], cb1j = cb1[j], lb1j = lb1[j];
    int g = t >> 4;
    float* ar = sa2 + g * 16;
    for (int it = 0; it < 8; ++it) {
        int nl = g * 8 + it;
        const float* r = sq + nl * 20;
        float4 q0 = *(const float4*)(r);
        float4 q1 = *(const float4*)(r + 4);
        float4 q2 = *(const float4*)(r + 8);
        float4 q3 = *(const float4*)(r + 12);
        float c2 = r[16], dn2 = r[17];
        float v2 = c2 * m2j + cb1j;
        v2 += q0.x * Mc[0] + q0.y * Mc[1] + q0.z * Mc[2] + q0.w * Mc[3];
        v2 += q1.x * Mc[4] + q1.y * Mc[5] + q1.z * Mc[6] + q1.w * Mc[7];
        v2 += q2.x * Mc[8] + q2.y * Mc[9] + q2.z * Mc[10] + q2.w * Mc[11];
        v2 += q3.x * Mc[12] + q3.y * Mc[13] + q3.z * Mc[14] + q3.w * Mc[15];
        ar[j] = fmaxf(v2, 0.f);          // wave-local
        float o = lb1j;
#pragma unroll
        for (int k = 0; k < 16; ++k) o += ar[k] * W1c[k];
        int n2 = blockIdx.x * 128 + nl;
        if (n2 < N_NODES) h2hat[(size_t)n2 * 16 + j] = dn2 * o;
    }
}

// layer 2: PINNED at random-64B-line fetch ceiling (67.5 µs across 3 configs,
// R9/R12/R14) — do not touch. 16 lanes/group, 4 nodes/group, unroll-8.
__global__ __launch_bounds__(256) void agg2_kernel(const u64* __restrict__ sorted,
                                                   const int* __restrict__ nodeoff,
                                                   const float* __restrict__ h2hat,
                                                   const float* __restrict__ dinv,
                                                   const float* __restrict__ cwr1,
                                                   const float* __restrict__ cb2,
                                                   const float* __restrict__ lw2,
                                                   const float* __restrict__ lb2,
                                                   float* __restrict__ h3) {
    __shared__ float sz[256];   // per (group, j) — wave-local roundtrip
    int t = threadIdx.x, j = t & 15, g = t >> 4;
    float W1c[16], W2c[16];
#pragma unroll
    for (int k = 0; k < 16; ++k) { W1c[k] = cwr1[k * 16 + j]; W2c[k] = lw2[k * 16 + j]; }
    float cb2j = cb2[j], lb2j = lb2[j];
    const float* zr = sz + g * 16;
    int nbase = blockIdx.x * 64 + g * 4;     // 3125 * 64 = 200000 exactly
#pragma unroll
    for (int it = 0; it < 4; ++it) {
        int n = nbase + it;
        int e0 = nodeoff[n];
        int e1 = (n < N_NODES - 1) ? nodeoff[n + 1] : N_EDGES;
        float q = 0.f;
        int i = e0;
        for (; i + 8 <= e1; i += 8) {
            u64 en0 = sorted[i],     en1 = sorted[i + 1], en2 = sorted[i + 2], en3 = sorted[i + 3];
            u64 en4 = sorted[i + 4], en5 = sorted[i + 5], en6 = sorted[i + 6], en7 = sorted[i + 7];
            float g0 = h2hat[(size_t)(en0 & 0x3ffffu) * 16 + j];
            float g1 = h2hat[(size_t)(en1 & 0x3ffffu) * 16 + j];
            float g2 = h2hat[(size_t)(en2 & 0x3ffffu) * 16 + j];
            float g3 = h2hat[(size_t)(en3 & 0x3ffffu) * 16 + j];
            float g4 = h2hat[(size_t)(en4 & 0x3ffffu) * 16 + j];
            float g5 = h2hat[(size_t)(en5 & 0x3ffffu) * 16 + j];
            float g6 = h2hat[(size_t)(en6 & 0x3ffffu) * 16 + j];
            float g7 = h2hat[(size_t)(en7 & 0x3ffffu) * 16 + j];
            q += __uint_as_float((unsigned)(en0 >> 32)) * g0
               + __uint_as_float((unsigned)(en1 >> 32)) * g1
               + __uint_as_float((unsigned)(en2 >> 32)) * g2
               + __uint_as_float((unsigned)(en3 >> 32)) * g3
               + __uint_as_float((unsigned)(en4 >> 32)) * g4
               + __uint_as_float((unsigned)(en5 >> 32)) * g5
               + __uint_as_float((unsigned)(en6 >> 32)) * g6
               + __uint_as_float((unsigned)(en7 >> 32)) * g7;
        }
        for (; i < e1; ++i) {
            u64 en = sorted[i];
            q += __uint_as_float((unsigned)(en >> 32)) * h2hat[(size_t)(en & 0x3ffffu) * 16 + j];
        }
        float dn = dinv[n];
        float z = dn * (q + h2hat[(size_t)n * 16 + j]);   // + dn^2 * h2[n]
        sz[t] = z;                                        // wave-local
        float v = cb2j;
#pragma unroll
        for (int k = 0; k < 16; ++k) v += zr[k] * W1c[k];
        float a = fmaxf(v, 0.f);
        sz[t] = a;                                        // wave-local overwrite
        float o = lb2j;
#pragma unroll
        for (int k = 0; k < 16; ++k) o += zr[k] * W2c[k];
        h3[(size_t)n * 16 + j] = o;
    }
}

// segmented pooling over sorted batch
#define POOL_RUN 16
__global__ __launch_bounds__(256) void pool_kernel(const float* __restrict__ h,
                                                   const int* __restrict__ batch,
                                                   float* __restrict__ num,
                                                   float* __restrict__ den) {
    int t = threadIdx.x;
    int tg = t >> 4, j = t & 15;
    int n_start = blockIdx.x * (16 * POOL_RUN) + tg * POOL_RUN;
    float accn = 0.f, accd = 0.f;
    int cur = -1;
    for (int k = 0; k < POOL_RUN; ++k) {
        int n = n_start + k;
        if (n >= N_NODES) break;
        int g = batch[n];
        if (g != cur) {
            if (cur >= 0) {
                atomicAdd(&num[cur * HD + j], accn);
                atomicAdd(&den[cur * HD + j], accd);
            }
            cur = g;
            accn = 0.f;
            accd = 0.f;
        }
        float v = h[(size_t)n * HD + j];
        float s = __expf(ALPHA_ * v);
        accn += v * s;
        accd += s;
    }
    if (cur >= 0) {
        atomicAdd(&num[cur * HD + j], accn);
        atomicAdd(&den[cur * HD + j], accd);
    }
}

__global__ __launch_bounds__(64) void final_kernel(const float* __restrict__ num,
                                                   const float* __restrict__ den,
                                                   const float* __restrict__ w1,
                                                   const float* __restrict__ b1,
                                                   const float* __restrict__ w2,
                                                   const float* __restrict__ b2,
                                                   const float* __restrict__ w3,
                                                   const float* __restrict__ b3,
                                                   float* __restrict__ out) {
    int g = blockIdx.x * blockDim.x + threadIdx.x;
    if (g >= N_GRAPHS) return;
    float p[16];
#pragma unroll
    for (int j = 0; j < 16; ++j) p[j] = num[g * HD + j] / den[g * HD + j];
    float t1[16];
#pragma unroll
    for (int j = 0; j < 16; ++j) {
        float acc = b1[j];
#pragma unroll
        for (int k = 0; k < 16; ++k) acc += p[k] * w1[k * 16 + j];
        t1[j] = fmaxf(acc, 0.f);
    }
    float t2[16];
#pragma unroll
    for (int j = 0; j < 16; ++j) {
        float acc = b2[j];
#pragma unroll
        for (int k = 0; k < 16; ++k) acc += t1[k] * w2[k * 16 + j];
        t2[j] = fmaxf(acc, 0.f);
    }
    float o = b3[0];
#pragma unroll
    for (int k = 0; k < 16; ++k) o += t2[k] * w3[k];
    out[g] = o;
}

extern "C" void kernel_launch(void* const* d_in, const int* in_sizes, int n_in,
                              void* d_out, int out_size, void* d_ws, size_t ws_size,
                              hipStream_t stream) {
    const float* x   = (const float*)d_in[0];
    const int*   ei  = (const int*)d_in[1];
    const int*   src = ei;
    const int*   dst = ei + N_EDGES;
    const int*   batch = (const int*)d_in[2];
    const float* ea  = (const float*)d_in[3];
    const float* cw0 = (const float*)d_in[4];
    const float* cwr = (const float*)d_in[5];
    const float* cb  = (const float*)d_in[6];
    const float* lw  = (const float*)d_in[7];
    const float* lb  = (const float*)d_in[8];
    const float* w1  = (const float*)d_in[9];
    const float* b1  = (const float*)d_in[10];
    const float* w2  = (const float*)d_in[11];
    const float* b2  = (const float*)d_in[12];
    const float* w3  = (const float*)d_in[13];
    const float* b3  = (const float*)d_in[14];
    float* out = (float*)d_out;

    // workspace layout (4-byte units) — blkhist reserve covers NBUCK*NBLKA_PAD = 613088
    float* ws      = (float*)d_ws;
    float* dinv    = ws;                                   // 200000
    float* s1v     = ws + 200000;                          // 200000
    int*   blkhist = (int*)(ws + 400000);                  // reserve 2443750 (uses 613088)
    float2* db0    = (float2*)(ws + 400000);               // aliases blkhist; 400000 floats
    int*   bstart  = blkhist + 2443750;                    // 392 (pad 784)
    int*   nodeoff = bstart + 784;                         // 200000 (pad 200010)
    float* num     = (float*)(nodeoff + 200010);           // 16384
    float* den     = num + 16384;                          // 16384
    float* Mm      = den + 16384;                          // 288 (unused, keeps offsets)
    float2* dx     = (float2*)(Mm + 288);                  // 400000 floats (even offset)
    u64* bucketed  = (u64*)((float*)dx + 400000);          // E u64 (even offset)
    u64* sorted    = bucketed + N_EDGES;                   // E u64
    float* h2hat   = (float*)bucketed;                     // alias: free after sortd
    float* h3      = h2hat + (size_t)N_NODES * HD;         // alias (bucketed region)

    hipMemsetAsync(num, 0, (size_t)2 * N_GRAPHS * HD * sizeof(float), stream);

    // full sort by dst: radix pass 1 (bucket dst>>9), pass 2 (in-bucket 9b dlow + dinv/dx)
    hist_kernel<<<NBLKA, 256, 0, stream>>>(dst, blkhist);
    scanA_kernel<<<NBUCK, 256, 0, stream>>>(blkhist, bstart);
    scanB_kernel<<<1, 256, 0, stream>>>(bstart);
    scatter_kernel<<<NBLKA, 256, 0, stream>>>(src, dst, ea, blkhist, bstart, bucketed);
    sortd_kernel<<<NBUCK, 1024, 0, stream>>>(bucketed, bstart, x, sorted, nodeoff, dinv, dx);

    // layer 0 (2 threads/node) -> db0={dinv,base0}, s1
    agg0_kernel<<<1563, 256, 0, stream>>>(sorted, nodeoff, dx, db0, s1v);
    // layer 1 (2 threads/node + fused prep + 2-stage epilogue) -> h2hat
    agg1_kernel<<<1563, 256, 0, stream>>>(sorted, nodeoff, db0, s1v,
                                          cw0, cb, lw, lb,
                                          cwr, cb + 16, lw + 256, lb + 16, h2hat);
    // layer 2 (simple unroll-8 gathers) -> h3
    agg2_kernel<<<3125, 256, 0, stream>>>(sorted, nodeoff, h2hat, dinv,
                                          cwr + 256, cb + 32, lw + 512, lb + 32, h3);

    pool_kernel<<<(N_NODES + 16 * POOL_RUN - 1) / (16 * POOL_RUN), 256, 0, stream>>>(h3, batch, num, den);
    final_kernel<<<(N_GRAPHS + 63) / 64, 64, 0, stream>>>(num, den, w1, b1, w2, b2, w3, b3, out);
}